// Round 22
// baseline (102.967 us; speedup 1.0000x reference)
//
#include <hip/hip_runtime.h>
#include <hip/hip_bf16.h>

#define Mpts 50000
#define Npts 50000
#define Hn 32
#define Cc 128
#define Kk 15
#define NCW 240   // K*CPG = 15*16
#define NBLK1 782 // MLP blocks in k1mix

typedef __attribute__((ext_vector_type(8))) short short8;
typedef __attribute__((ext_vector_type(4))) float f32x4;
typedef __attribute__((ext_vector_type(2))) float f32x2;
typedef unsigned int u32;

__device__ inline ushort f2bf(float f) {
  __hip_bfloat16 h = __float2bfloat16(f);
  return *reinterpret_cast<ushort*>(&h);
}

// ====== K0w: weights transpose + pad rows + stats zero (5 blocks) ============
__global__ __launch_bounds__(256) void k0_pre(
    const float* __restrict__ W1, const float* __restrict__ W2,
    ushort* __restrict__ sfbL, ushort* __restrict__ sfbH,
    ushort* __restrict__ W1t, ushort* __restrict__ W2t,
    float* __restrict__ stats)
{
  __shared__ ushort TT[240][66];
  const int t = threadIdx.x;
  const int b = blockIdx.x;
  if (b < 2) {                       // ---- W1: 64 k-rows x 128 n ----
    const int k0 = b * 64;
#pragma unroll
    for (int i = 0; i < 32; ++i) {
      int e = t + i * 256;
      int r = e >> 7, c = e & 127;
      TT[c][r] = f2bf(W1[(size_t)(k0 + r) * Cc + c]);
    }
    __syncthreads();
    int n = t >> 1, half = t & 1;
    union { short8 v[4]; ushort u[32]; } pk;
#pragma unroll
    for (int i = 0; i < 32; ++i) pk.u[i] = TT[n][half * 32 + i];
#pragma unroll
    for (int q = 0; q < 4; ++q)
      *(short8*)(W1t + (size_t)n * Cc + k0 + half * 32 + q * 8) = pk.v[q];
  } else if (b < 4) {                // ---- W2: 64 k-rows x 240 n ----
    const int k0 = (b - 2) * 64;
    for (int i = 0; i < 60; ++i) {
      int e = t + i * 256;
      int r = e / 240, c = e % 240;
      TT[c][r] = f2bf(W2[(size_t)(k0 + r) * NCW + c]);
    }
    __syncthreads();
    if (t < 240) {
      union { short8 v[8]; ushort u[64]; } pk;
#pragma unroll
      for (int i = 0; i < 64; ++i) pk.u[i] = TT[t][i];
#pragma unroll
      for (int q = 0; q < 8; ++q)
        *(short8*)(W2t + (size_t)t * Cc + k0 + q * 8) = pk.v[q];
    }
  } else {                           // ---- pad rows + stats zero ----
    short8 z = short8{0,0,0,0,0,0,0,0};
    if (t < 8)                  *(short8*)(sfbL + (size_t)Npts * 64 + t * 8) = z;
    else if (t < 16)            *(short8*)(sfbH + (size_t)Npts * 64 + (t - 8) * 8) = z;
    if (t < 128) {
      float4 z4 = make_float4(0.f, 0.f, 0.f, 0.f);
      *(float4*)(stats + t * 4) = z4;
    }
  }
}

// ====== K1mix: interleaved 1:8 — bid%9==0 -> MLP block bid/9; else geometry ==
__global__ __launch_bounds__(256, 3) void k1_mix(
    const float* __restrict__ sfeat, const ushort* __restrict__ W1t,
    const float* __restrict__ b1, const ushort* __restrict__ W2t,
    const float* __restrict__ b2, ushort* __restrict__ sfbL,
    ushort* __restrict__ sfbH, ushort* __restrict__ cw,
    float* __restrict__ stats,
    const float* __restrict__ q_pts, const float* __restrict__ s_pts,
    const int* __restrict__ nb, const float* __restrict__ kp,
    u32* __restrict__ geomP)
{
  __shared__ __align__(16) ushort shA[64 * 128];    // 16 KB: A tile -> h tile
  __shared__ __align__(16) ushort shW[128 * 128];   // 32 KB: W halves / bounce
  __shared__ float red[2][15][4];
  __shared__ float kptS[45];

  const int t = threadIdx.x;
  const int bid = blockIdx.x;
  const int q9 = bid / 9, r9 = bid - q9 * 9;

  if (r9 != 0) {                    // ================= geometry block ========
    if (t < 45) kptS[t] = kp[t];
    __syncthreads();
    const int gtid = (q9 * 8 + (r9 - 1)) * 256 + t;
    const int m = gtid >> 5;
    int idx = nb[gtid]; if (idx > Npts) idx = Npts;
    float qx = q_pts[m * 3 + 0], qy = q_pts[m * 3 + 1], qz = q_pts[m * 3 + 2];
    float px, py, pz;
    if (idx < Npts) { px = s_pts[idx * 3 + 0]; py = s_pts[idx * 3 + 1]; pz = s_pts[idx * 3 + 2]; }
    else            { px = 1.0e6f; py = 1.0e6f; pz = 1.0e6f; }
    float nx = px - qx, ny = py - qy, nz = pz - qz;
    int ksel = 0; float best = 1e30f;
#pragma unroll
    for (int k = 0; k < Kk; ++k) {
      float dx = nx - kptS[k * 3 + 0], dy = ny - kptS[k * 3 + 1], dz = nz - kptS[k * 3 + 2];
      float d = dx * dx + dy * dy + dz * dz;
      if (d < best) { best = d; ksel = k; }
    }
    float infl = 1.f - sqrtf(best);
    infl = infl > 0.f ? infl : 0.f;
    geomP[gtid] = (__float_as_uint(infl) & 0xFFFFFFF0u) | (u32)ksel;
    return;
  }

  // ================= MLP block (R20 structure) =================
  const int mlpBlk = q9;            // 0..781
  const int r0 = mlpBlk * 64;
  const int wid = t >> 6, lane = t & 63;
  const int l16 = lane & 15, lq = lane >> 4;

  // ---- issue A loads (fp32 from sfeat, HBM) + W1 loads (L2) ----
  float4 fA[4], fB[4];
#pragma unroll
  for (int p = 0; p < 4; ++p) {
    int id = p * 256 + t;
    int r = id >> 4, c = id & 15;
    int g = r0 + r;
    fA[p] = make_float4(0.f, 0.f, 0.f, 0.f);
    fB[p] = make_float4(0.f, 0.f, 0.f, 0.f);
    if (g < Mpts) {
      const float* src = sfeat + (size_t)g * Cc + c * 8;
      fA[p] = *(const float4*)(src);
      fB[p] = *(const float4*)(src + 4);
    }
  }
  uint4 wv[8];
#pragma unroll
  for (int p = 0; p < 8; ++p) {
    int id = p * 256 + t;
    int r = id >> 4, c = id & 15;
    wv[p] = *(const uint4*)(W1t + r * Cc + c * 8);
  }
  asm volatile("" :: "v"(wv[0].x), "v"(wv[1].x), "v"(wv[2].x), "v"(wv[3].x),
                     "v"(wv[4].x), "v"(wv[5].x), "v"(wv[6].x), "v"(wv[7].x),
                     "v"(fA[0].x), "v"(fA[1].x), "v"(fA[2].x), "v"(fA[3].x),
                     "v"(fB[0].x), "v"(fB[1].x), "v"(fB[2].x), "v"(fB[3].x));
#pragma unroll
  for (int p = 0; p < 8; ++p) {
    int id = p * 256 + t;
    int r = id >> 4, c = id & 15;
    *(uint4*)((char*)shW + ((r * 256 + c * 16) ^ ((r & 7) << 4))) = wv[p];
  }
#pragma unroll
  for (int p = 0; p < 4; ++p) {
    int id = p * 256 + t;
    int r = id >> 4, c = id & 15;
    int g = r0 + r;
    union { short8 s; ushort u[8]; } pk;
    pk.u[0] = f2bf(fA[p].x); pk.u[1] = f2bf(fA[p].y); pk.u[2] = f2bf(fA[p].z); pk.u[3] = f2bf(fA[p].w);
    pk.u[4] = f2bf(fB[p].x); pk.u[5] = f2bf(fB[p].y); pk.u[6] = f2bf(fB[p].z); pk.u[7] = f2bf(fB[p].w);
    if (g < Mpts) {
      ushort* dst = (c < 8 ? sfbL : sfbH) + (size_t)g * 64 + (c & 7) * 8;
      *(short8*)dst = pk.s;
    }
    *(short8*)((char*)shA + ((r * 256 + c * 16) ^ ((r & 7) << 4))) = pk.s;
  }
  __syncthreads();

  const int arow = wid * 16 + l16;
  const int axor = (arow & 7) << 4;

  // ---- stage 1: h[16 rows][128] ----
  f32x4 acc1[8];
#pragma unroll
  for (int nt = 0; nt < 8; ++nt) acc1[nt] = f32x4{0.f, 0.f, 0.f, 0.f};
#pragma unroll
  for (int kt = 0; kt < 4; ++kt) {
    const int koff2 = (kt * 32 + lq * 8) * 2;
    short8 a = *(const short8*)((const char*)shA + ((arow * 256 + koff2) ^ axor));
#pragma unroll
    for (int nt = 0; nt < 8; ++nt) {
      int wrow = nt * 16 + l16;
      short8 b = *(const short8*)((const char*)shW + ((wrow * 256 + koff2) ^ ((wrow & 7) << 4)));
      acc1[nt] = __builtin_amdgcn_mfma_f32_16x16x32_bf16(a, b, acc1[nt], 0, 0, 0);
    }
  }
  // bias + LeakyReLU -> shA (own rows; no barrier needed)
#pragma unroll
  for (int nt = 0; nt < 8; ++nt) {
    int col = nt * 16 + l16;
    float bias = b1[col];
#pragma unroll
    for (int reg = 0; reg < 4; ++reg) {
      float h = acc1[nt][reg] + bias;
      h = h >= 0.f ? h : 0.1f * h;
      int row = wid * 16 + lq * 4 + reg;
      int byte = ((row * 256) + col * 2) ^ ((row & 7) << 4);
      *(ushort*)((char*)shA + byte) = f2bf(h);
    }
  }

  // ---- stage 2: both W2 halves; accumulators kept in registers ----
  f32x4 acc2[8], acc3[7];
#pragma unroll
  for (int j = 0; j < 8; ++j) acc2[j] = f32x4{0.f, 0.f, 0.f, 0.f};
#pragma unroll
  for (int j = 0; j < 7; ++j) acc3[j] = f32x4{0.f, 0.f, 0.f, 0.f};

  __syncthreads();
  {
    uint4 wv2[8];
#pragma unroll
    for (int p = 0; p < 8; ++p) {
      int id = p * 256 + t;
      int r = id >> 4, c = id & 15;
      wv2[p] = *(const uint4*)(W2t + (size_t)r * Cc + c * 8);
    }
    asm volatile("" :: "v"(wv2[0].x), "v"(wv2[1].x), "v"(wv2[2].x), "v"(wv2[3].x),
                       "v"(wv2[4].x), "v"(wv2[5].x), "v"(wv2[6].x), "v"(wv2[7].x));
#pragma unroll
    for (int p = 0; p < 8; ++p) {
      int id = p * 256 + t;
      int r = id >> 4, c = id & 15;
      *(uint4*)((char*)shW + ((r * 256 + c * 16) ^ ((r & 7) << 4))) = wv2[p];
    }
  }
  __syncthreads();
#pragma unroll
  for (int kt = 0; kt < 4; ++kt) {
    const int koff2 = (kt * 32 + lq * 8) * 2;
    short8 a = *(const short8*)((const char*)shA + ((arow * 256 + koff2) ^ axor));
#pragma unroll
    for (int j = 0; j < 8; ++j) {
      int wrow = j * 16 + l16;
      short8 b = *(const short8*)((const char*)shW + ((wrow * 256 + koff2) ^ ((wrow & 7) << 4)));
      acc2[j] = __builtin_amdgcn_mfma_f32_16x16x32_bf16(a, b, acc2[j], 0, 0, 0);
    }
  }

  __syncthreads();
  {
    uint4 wv2[7];
#pragma unroll
    for (int p = 0; p < 7; ++p) {
      int id = p * 256 + t;
      int r = id >> 4, c = id & 15;
      wv2[p] = *(const uint4*)(W2t + (size_t)(128 + r) * Cc + c * 8);
    }
    asm volatile("" :: "v"(wv2[0].x), "v"(wv2[1].x), "v"(wv2[2].x), "v"(wv2[3].x),
                       "v"(wv2[4].x), "v"(wv2[5].x), "v"(wv2[6].x));
#pragma unroll
    for (int p = 0; p < 7; ++p) {
      int id = p * 256 + t;
      int r = id >> 4, c = id & 15;
      *(uint4*)((char*)shW + ((r * 256 + c * 16) ^ ((r & 7) << 4))) = wv2[p];
    }
  }
  __syncthreads();
#pragma unroll
  for (int kt = 0; kt < 4; ++kt) {
    const int koff2 = (kt * 32 + lq * 8) * 2;
    short8 a = *(const short8*)((const char*)shA + ((arow * 256 + koff2) ^ axor));
#pragma unroll
    for (int j = 0; j < 7; ++j) {
      int wrow = j * 16 + l16;
      short8 b = *(const short8*)((const char*)shW + ((wrow * 256 + koff2) ^ ((wrow & 7) << 4)));
      acc3[j] = __builtin_amdgcn_mfma_f32_16x16x32_bf16(a, b, acc3[j], 0, 0, 0);
    }
  }
  __syncthreads();                 // done reading shW -> reuse as bounce buffer

  // ---- bias + stats + bounce tile to LDS [64][244] ----
  ushort* shB = shW;
  float s[15], ss[15];
#pragma unroll
  for (int j = 0; j < 15; ++j) { s[j] = 0.f; ss[j] = 0.f; }
  const int rowb = wid * 16 + lq * 4;
#pragma unroll
  for (int j = 0; j < 15; ++j) {
    int col = j * 16 + l16;
    float bias = b2[col];
#pragma unroll
    for (int reg = 0; reg < 4; ++reg) {
      float v = (j < 8 ? acc2[j][reg] : acc3[j - 8][reg]) + bias;
      shB[(rowb + reg) * 244 + col] = f2bf(v);
      if (r0 + rowb + reg < Mpts) { s[j] += v; ss[j] += v * v; }
    }
  }
  __syncthreads();

  // ---- coalesced cw stores: 1920 x 16B chunks ----
  {
    char* cwB = (char*)cw + (size_t)r0 * 480;
#pragma unroll
    for (int i = 0; i < 8; ++i) {
      int gid = i * 256 + t;
      if (gid < 1920) {
        int row = gid / 30;
        int rem = (gid - row * 30) * 16;
        if (r0 + row < Mpts) {
          uint4 v = *(const uint4*)((const char*)shB + row * 488 + rem);
          *(uint4*)(cwB + (size_t)row * 480 + rem) = v;
        }
      }
    }
  }

  // ---- stats reduce + replicated atomics ----
#pragma unroll
  for (int j = 0; j < 15; ++j) {
    for (int off = 32; off > 0; off >>= 1) {
      s[j]  += __shfl_xor(s[j],  off);
      ss[j] += __shfl_xor(ss[j], off);
    }
  }
  if (lane == 0) {
#pragma unroll
    for (int j = 0; j < 15; ++j) { red[0][j][wid] = s[j]; red[1][j][wid] = ss[j]; }
  }
  __syncthreads();
  float* st = stats + (mlpBlk & 7) * 64;
  if (t < 15) {
    float S = red[0][t][0] + red[0][t][1] + red[0][t][2] + red[0][t][3];
    atomicAdd(&st[t], S);
  } else if (t >= 32 && t < 47) {
    int j = t - 32;
    float SS = red[1][j][0] + red[1][j][1] + red[1][j][2] + red[1][j][3];
    atomicAdd(&st[32 + j], SS);
  }
}

// ====== K3: half-split gather-sum from split arrays (full-line rows) =========
__global__ __launch_bounds__(256) void k3_out(
    const ushort* __restrict__ sfbL, const ushort* __restrict__ sfbH,
    const int* __restrict__ nb, const u32* __restrict__ geomP,
    const float* __restrict__ gn_w, const float* __restrict__ gn_b,
    const float* __restrict__ stats, const ushort* __restrict__ cw,
    float* __restrict__ out)
{
  __shared__ float Atab[255], Btab[255];        // stride 17
  __shared__ float mus[16], rss[16];
  __shared__ float wtab[4][2][8][33];           // [wave][pt][chunk][h+pad]
  const int t = threadIdx.x;

  if (t < 15) {
    float S = 0.f, SS = 0.f;
#pragma unroll
    for (int r = 0; r < 8; ++r) { S += stats[r * 64 + t]; SS += stats[r * 64 + 32 + t]; }
    const float inv = 1.0f / (16.0f * (float)Mpts);
    float mu = S * inv;
    float var = SS * inv - mu * mu;
    mus[t] = mu;
    rss[t] = rsqrtf(var + 1e-5f);
  }
  __syncthreads();
  if (t < 240) {
    int k = t >> 4, c = t & 15;
    float a = rss[k] * gn_w[t];
    Atab[k * 17 + c] = a;
    Btab[k * 17 + c] = gn_b[t] - mus[k] * a;
  }
  __syncthreads();

  const int half = (blockIdx.x >= 6250) ? 1 : 0;
  const int pblk = blockIdx.x - half * 6250;
  const int wid = t >> 6, lane = t & 63;
  const int mbase = pblk * 8 + wid * 2;
  const int gtid = pblk * 256 + t;              // == mbase*32 + lane
  const int ch = lane & 7, hlane = (lane >> 3) & 3, p = lane >> 5;
  const int half8 = half * 8;

  u32 g = geomP[gtid];
  int idxv = nb[gtid]; if (idxv > Npts) idxv = Npts;

  // ---- issue 8 gathers from the half's own 128B-row array ----
  const uint4* fb = (const uint4*)(half ? sfbH : sfbL);
  uint4 fv[8];
#pragma unroll
  for (int j = 0; j < 8; ++j) {
    int ih = __shfl(idxv, (p << 5) | (hlane + 4 * j));
    fv[j] = fb[ih * 8 + ch];                    // row = 8 uint4 = 128 B
  }

  // ---- build wtab for both points while gathers fly (wave-private) ----
  {
    int h = lane >> 1, c0 = (lane & 1) * 4;
#pragma unroll
    for (int q = 0; q < 2; ++q) {
      u32 gp = __shfl((int)g, (q << 5) | h);
      int kh = gp & 15;
      float wI = __uint_as_float(gp & 0xFFFFFFF0u);
      uint2 cwv = *(const uint2*)(cw + (size_t)(mbase + q) * NCW + kh * 16 + half8 + c0);
      const float* Ar = &Atab[kh * 17 + half8 + c0];
      const float* Br = &Btab[kh * 17 + half8 + c0];
      float v0 = __uint_as_float(cwv.x << 16);
      float v1 = __uint_as_float(cwv.x & 0xffff0000u);
      float v2 = __uint_as_float(cwv.y << 16);
      float v3 = __uint_as_float(cwv.y & 0xffff0000u);
      wtab[wid][q][c0 + 0][h] = fmaf(v0, Ar[0], Br[0]) * wI;
      wtab[wid][q][c0 + 1][h] = fmaf(v1, Ar[1], Br[1]) * wI;
      wtab[wid][q][c0 + 2][h] = fmaf(v2, Ar[2], Br[2]) * wI;
      wtab[wid][q][c0 + 3][h] = fmaf(v3, Ar[3], Br[3]) * wI;
    }
  }

  asm volatile("" :: "v"(fv[0].x), "v"(fv[1].x), "v"(fv[2].x), "v"(fv[3].x),
                     "v"(fv[4].x), "v"(fv[5].x), "v"(fv[6].x), "v"(fv[7].x));

  // ---- main: 8 iters, 1 ds_read + masked decode + 4 pk_fma ----
  f32x2 a0 = {0.f, 0.f}, a1 = {0.f, 0.f}, a2 = {0.f, 0.f}, a3 = {0.f, 0.f};
#pragma unroll
  for (int j = 0; j < 8; ++j) {
    float w = wtab[wid][p][ch][hlane + 4 * j];
    f32x2 w2 = {w, w};
    u32 ux = fv[j].x, uy = fv[j].y, uz = fv[j].z, uw = fv[j].w;
    f32x2 q0 = {__uint_as_float(ux << 16), __uint_as_float(ux & 0xffff0000u)};
    f32x2 q1 = {__uint_as_float(uy << 16), __uint_as_float(uy & 0xffff0000u)};
    f32x2 q2 = {__uint_as_float(uz << 16), __uint_as_float(uz & 0xffff0000u)};
    f32x2 q3 = {__uint_as_float(uw << 16), __uint_as_float(uw & 0xffff0000u)};
    a0 = __builtin_elementwise_fma(q0, w2, a0);
    a1 = __builtin_elementwise_fma(q1, w2, a1);
    a2 = __builtin_elementwise_fma(q2, w2, a2);
    a3 = __builtin_elementwise_fma(q3, w2, a3);
  }
#pragma unroll
  for (int off = 8; off <= 16; off <<= 1) {
    a0[0] += __shfl_xor(a0[0], off); a0[1] += __shfl_xor(a0[1], off);
    a1[0] += __shfl_xor(a1[0], off); a1[1] += __shfl_xor(a1[1], off);
    a2[0] += __shfl_xor(a2[0], off); a2[1] += __shfl_xor(a2[1], off);
    a3[0] += __shfl_xor(a3[0], off); a3[1] += __shfl_xor(a3[1], off);
  }
  if ((lane & 24) == 0) {
    float* op = out + (size_t)(mbase + p) * Cc + half * 64 + ch * 8;
    float4 o0; o0.x = a0[0]; o0.y = a0[1]; o0.z = a1[0]; o0.w = a1[1];
    float4 o1; o1.x = a2[0]; o1.y = a2[1]; o1.z = a3[0]; o1.w = a3[1];
    *(float4*)(op)     = o0;
    *(float4*)(op + 4) = o1;
  }
}

// ================= launcher ==================================================
extern "C" void kernel_launch(void* const* d_in, const int* in_sizes, int n_in,
                              void* d_out, int out_size, void* d_ws, size_t ws_size,
                              hipStream_t stream) {
  const float* q_pts  = (const float*)d_in[0];
  const float* s_pts  = (const float*)d_in[1];
  const float* sfeat  = (const float*)d_in[2];
  const int*   nb     = (const int*)d_in[3];
  const float* kp     = (const float*)d_in[4];
  const float* W1     = (const float*)d_in[5];
  const float* b1     = (const float*)d_in[6];
  const float* W2     = (const float*)d_in[7];
  const float* b2     = (const float*)d_in[8];
  const float* gn_w   = (const float*)d_in[9];
  const float* gn_b   = (const float*)d_in[10];
  float* out   = (float*)d_out;

  // ws layout (bytes):
  //   0          stats   (8 replicas x 64 f32, padded to 4096)
  //   4096       sfbL    bf16 (50000+1)x64 = 6,400,128
  //   6404224    sfbH    bf16 (50000+1)x64 = 6,400,128
  //   12804352   W1t     bf16 128x128 = 32768
  //   12837120   W2t     bf16 240x128 = 61440
  //   12898560   cw      bf16 50000x240 = 24,000,000
  //   36898560   geomP   u32 50000x32 = 6,400,000
  char* wsb = (char*)d_ws;
  float*  stats = (float*)wsb;
  ushort* sfbL  = (ushort*)(wsb + 4096);
  ushort* sfbH  = (ushort*)(wsb + 6404224);
  ushort* W1t   = (ushort*)(wsb + 12804352);
  ushort* W2t   = (ushort*)(wsb + 12837120);
  ushort* cwb   = (ushort*)(wsb + 12898560);
  u32*    geomP = (u32*)   (wsb + 36898560);

  k0_pre<<<5, 256, 0, stream>>>(W1, W2, sfbL, sfbH, W1t, W2t, stats);
  k1_mix<<<NBLK1 + 6250, 256, 0, stream>>>(sfeat, W1t, b1, W2t, b2,
                                           sfbL, sfbH, cwb, stats,
                                           q_pts, s_pts, nb, kp, geomP);
  k3_out<<<12500, 256, 0, stream>>>(sfbL, sfbH, nb, geomP, gn_w, gn_b,
                                    stats, cwb, out);
}

// Round 23
// 93.874 us; speedup vs baseline: 1.0969x; 1.0969x over previous
//
#include <hip/hip_runtime.h>
#include <hip/hip_bf16.h>

#define Mpts 50000
#define Npts 50000
#define Hn 32
#define Cc 128
#define Kk 15
#define NCW 240   // K*CPG = 15*16
#define NBLK1 782 // MLP blocks in k1mix

typedef __attribute__((ext_vector_type(8))) short short8;
typedef __attribute__((ext_vector_type(4))) float f32x4;
typedef __attribute__((ext_vector_type(2))) float f32x2;
typedef unsigned int u32;

__device__ inline ushort f2bf(float f) {
  __hip_bfloat16 h = __float2bfloat16(f);
  return *reinterpret_cast<ushort*>(&h);
}

// ====== K0w: weights transpose + pad rows + stats zero (5 blocks) ============
__global__ __launch_bounds__(256) void k0_pre(
    const float* __restrict__ W1, const float* __restrict__ W2,
    ushort* __restrict__ sfbL, ushort* __restrict__ sfbH,
    ushort* __restrict__ W1t, ushort* __restrict__ W2t,
    float* __restrict__ stats)
{
  __shared__ ushort TT[240][66];
  const int t = threadIdx.x;
  const int b = blockIdx.x;
  if (b < 2) {                       // ---- W1: 64 k-rows x 128 n ----
    const int k0 = b * 64;
#pragma unroll
    for (int i = 0; i < 32; ++i) {
      int e = t + i * 256;
      int r = e >> 7, c = e & 127;
      TT[c][r] = f2bf(W1[(size_t)(k0 + r) * Cc + c]);
    }
    __syncthreads();
    int n = t >> 1, half = t & 1;
    union { short8 v[4]; ushort u[32]; } pk;
#pragma unroll
    for (int i = 0; i < 32; ++i) pk.u[i] = TT[n][half * 32 + i];
#pragma unroll
    for (int q = 0; q < 4; ++q)
      *(short8*)(W1t + (size_t)n * Cc + k0 + half * 32 + q * 8) = pk.v[q];
  } else if (b < 4) {                // ---- W2: 64 k-rows x 240 n ----
    const int k0 = (b - 2) * 64;
    for (int i = 0; i < 60; ++i) {
      int e = t + i * 256;
      int r = e / 240, c = e % 240;
      TT[c][r] = f2bf(W2[(size_t)(k0 + r) * NCW + c]);
    }
    __syncthreads();
    if (t < 240) {
      union { short8 v[8]; ushort u[64]; } pk;
#pragma unroll
      for (int i = 0; i < 64; ++i) pk.u[i] = TT[t][i];
#pragma unroll
      for (int q = 0; q < 8; ++q)
        *(short8*)(W2t + (size_t)t * Cc + k0 + q * 8) = pk.v[q];
    }
  } else {                           // ---- pad rows + stats zero ----
    short8 z = short8{0,0,0,0,0,0,0,0};
    if (t < 8)                  *(short8*)(sfbL + (size_t)Npts * 64 + t * 8) = z;
    else if (t < 16)            *(short8*)(sfbH + (size_t)Npts * 64 + (t - 8) * 8) = z;
    if (t < 128) {
      float4 z4 = make_float4(0.f, 0.f, 0.f, 0.f);
      *(float4*)(stats + t * 4) = z4;
    }
  }
}

// ====== K1mix: blocks<782 = fused MLP; blocks>=782 = geometry ================
__global__ __launch_bounds__(256, 3) void k1_mix(
    const float* __restrict__ sfeat, const ushort* __restrict__ W1t,
    const float* __restrict__ b1, const ushort* __restrict__ W2t,
    const float* __restrict__ b2, ushort* __restrict__ sfbL,
    ushort* __restrict__ sfbH, ushort* __restrict__ cw,
    float* __restrict__ stats,
    const float* __restrict__ q_pts, const float* __restrict__ s_pts,
    const int* __restrict__ nb, const float* __restrict__ kp,
    u32* __restrict__ geomP)
{
  __shared__ __align__(16) ushort shA[64 * 128];    // 16 KB: A tile -> h tile
  __shared__ __align__(16) ushort shW[128 * 128];   // 32 KB: W halves / bounce
  __shared__ float red[2][15][4];
  __shared__ float kptS[45];

  const int t = threadIdx.x;

  if (blockIdx.x >= NBLK1) {        // ================= geometry block ========
    if (t < 45) kptS[t] = kp[t];
    __syncthreads();
    const int gtid = (blockIdx.x - NBLK1) * 256 + t;
    const int m = gtid >> 5;
    int idx = nb[gtid]; if (idx > Npts) idx = Npts;
    float qx = q_pts[m * 3 + 0], qy = q_pts[m * 3 + 1], qz = q_pts[m * 3 + 2];
    float px, py, pz;
    if (idx < Npts) { px = s_pts[idx * 3 + 0]; py = s_pts[idx * 3 + 1]; pz = s_pts[idx * 3 + 2]; }
    else            { px = 1.0e6f; py = 1.0e6f; pz = 1.0e6f; }
    float nx = px - qx, ny = py - qy, nz = pz - qz;
    int ksel = 0; float best = 1e30f;
#pragma unroll
    for (int k = 0; k < Kk; ++k) {
      float dx = nx - kptS[k * 3 + 0], dy = ny - kptS[k * 3 + 1], dz = nz - kptS[k * 3 + 2];
      float d = dx * dx + dy * dy + dz * dz;
      if (d < best) { best = d; ksel = k; }
    }
    float infl = 1.f - sqrtf(best);
    infl = infl > 0.f ? infl : 0.f;
    geomP[gtid] = (__float_as_uint(infl) & 0xFFFFFFF0u) | (u32)ksel;
    return;
  }

  // ================= MLP block =================
  const int r0 = blockIdx.x * 64;
  const int wid = t >> 6, lane = t & 63;
  const int l16 = lane & 15, lq = lane >> 4;

  // ---- issue A loads (fp32 from sfeat, HBM) + W1 loads (L2) ----
  float4 fA[4], fB[4];
#pragma unroll
  for (int p = 0; p < 4; ++p) {
    int id = p * 256 + t;
    int r = id >> 4, c = id & 15;
    int g = r0 + r;
    fA[p] = make_float4(0.f, 0.f, 0.f, 0.f);
    fB[p] = make_float4(0.f, 0.f, 0.f, 0.f);
    if (g < Mpts) {
      const float* src = sfeat + (size_t)g * Cc + c * 8;
      fA[p] = *(const float4*)(src);
      fB[p] = *(const float4*)(src + 4);
    }
  }
  uint4 wv[8];
#pragma unroll
  for (int p = 0; p < 8; ++p) {
    int id = p * 256 + t;
    int r = id >> 4, c = id & 15;
    wv[p] = *(const uint4*)(W1t + r * Cc + c * 8);
  }
  asm volatile("" :: "v"(wv[0].x), "v"(wv[1].x), "v"(wv[2].x), "v"(wv[3].x),
                     "v"(wv[4].x), "v"(wv[5].x), "v"(wv[6].x), "v"(wv[7].x),
                     "v"(fA[0].x), "v"(fA[1].x), "v"(fA[2].x), "v"(fA[3].x),
                     "v"(fB[0].x), "v"(fB[1].x), "v"(fB[2].x), "v"(fB[3].x));
#pragma unroll
  for (int p = 0; p < 8; ++p) {
    int id = p * 256 + t;
    int r = id >> 4, c = id & 15;
    *(uint4*)((char*)shW + ((r * 256 + c * 16) ^ ((r & 7) << 4))) = wv[p];
  }
#pragma unroll
  for (int p = 0; p < 4; ++p) {
    int id = p * 256 + t;
    int r = id >> 4, c = id & 15;
    int g = r0 + r;
    union { short8 s; ushort u[8]; } pk;
    pk.u[0] = f2bf(fA[p].x); pk.u[1] = f2bf(fA[p].y); pk.u[2] = f2bf(fA[p].z); pk.u[3] = f2bf(fA[p].w);
    pk.u[4] = f2bf(fB[p].x); pk.u[5] = f2bf(fB[p].y); pk.u[6] = f2bf(fB[p].z); pk.u[7] = f2bf(fB[p].w);
    if (g < Mpts) {
      ushort* dst = (c < 8 ? sfbL : sfbH) + (size_t)g * 64 + (c & 7) * 8;
      *(short8*)dst = pk.s;
    }
    *(short8*)((char*)shA + ((r * 256 + c * 16) ^ ((r & 7) << 4))) = pk.s;
  }
  __syncthreads();

  const int arow = wid * 16 + l16;
  const int axor = (arow & 7) << 4;

  // ---- stage 1: h[16 rows][128] ----
  f32x4 acc1[8];
#pragma unroll
  for (int nt = 0; nt < 8; ++nt) acc1[nt] = f32x4{0.f, 0.f, 0.f, 0.f};
#pragma unroll
  for (int kt = 0; kt < 4; ++kt) {
    const int koff2 = (kt * 32 + lq * 8) * 2;
    short8 a = *(const short8*)((const char*)shA + ((arow * 256 + koff2) ^ axor));
#pragma unroll
    for (int nt = 0; nt < 8; ++nt) {
      int wrow = nt * 16 + l16;
      short8 b = *(const short8*)((const char*)shW + ((wrow * 256 + koff2) ^ ((wrow & 7) << 4)));
      acc1[nt] = __builtin_amdgcn_mfma_f32_16x16x32_bf16(a, b, acc1[nt], 0, 0, 0);
    }
  }
  // bias + LeakyReLU -> shA (own rows; no barrier needed)
#pragma unroll
  for (int nt = 0; nt < 8; ++nt) {
    int col = nt * 16 + l16;
    float bias = b1[col];
#pragma unroll
    for (int reg = 0; reg < 4; ++reg) {
      float h = acc1[nt][reg] + bias;
      h = h >= 0.f ? h : 0.1f * h;
      int row = wid * 16 + lq * 4 + reg;
      int byte = ((row * 256) + col * 2) ^ ((row & 7) << 4);
      *(ushort*)((char*)shA + byte) = f2bf(h);
    }
  }

  // ---- stage 2: both W2 halves; accumulators kept in registers ----
  f32x4 acc2[8], acc3[7];
#pragma unroll
  for (int j = 0; j < 8; ++j) acc2[j] = f32x4{0.f, 0.f, 0.f, 0.f};
#pragma unroll
  for (int j = 0; j < 7; ++j) acc3[j] = f32x4{0.f, 0.f, 0.f, 0.f};

  __syncthreads();
  {
    uint4 wv2[8];
#pragma unroll
    for (int p = 0; p < 8; ++p) {
      int id = p * 256 + t;
      int r = id >> 4, c = id & 15;
      wv2[p] = *(const uint4*)(W2t + (size_t)r * Cc + c * 8);
    }
    asm volatile("" :: "v"(wv2[0].x), "v"(wv2[1].x), "v"(wv2[2].x), "v"(wv2[3].x),
                       "v"(wv2[4].x), "v"(wv2[5].x), "v"(wv2[6].x), "v"(wv2[7].x));
#pragma unroll
    for (int p = 0; p < 8; ++p) {
      int id = p * 256 + t;
      int r = id >> 4, c = id & 15;
      *(uint4*)((char*)shW + ((r * 256 + c * 16) ^ ((r & 7) << 4))) = wv2[p];
    }
  }
  __syncthreads();
#pragma unroll
  for (int kt = 0; kt < 4; ++kt) {
    const int koff2 = (kt * 32 + lq * 8) * 2;
    short8 a = *(const short8*)((const char*)shA + ((arow * 256 + koff2) ^ axor));
#pragma unroll
    for (int j = 0; j < 8; ++j) {
      int wrow = j * 16 + l16;
      short8 b = *(const short8*)((const char*)shW + ((wrow * 256 + koff2) ^ ((wrow & 7) << 4)));
      acc2[j] = __builtin_amdgcn_mfma_f32_16x16x32_bf16(a, b, acc2[j], 0, 0, 0);
    }
  }

  __syncthreads();
  {
    uint4 wv2[7];
#pragma unroll
    for (int p = 0; p < 7; ++p) {
      int id = p * 256 + t;
      int r = id >> 4, c = id & 15;
      wv2[p] = *(const uint4*)(W2t + (size_t)(128 + r) * Cc + c * 8);
    }
    asm volatile("" :: "v"(wv2[0].x), "v"(wv2[1].x), "v"(wv2[2].x), "v"(wv2[3].x),
                       "v"(wv2[4].x), "v"(wv2[5].x), "v"(wv2[6].x));
#pragma unroll
    for (int p = 0; p < 7; ++p) {
      int id = p * 256 + t;
      int r = id >> 4, c = id & 15;
      *(uint4*)((char*)shW + ((r * 256 + c * 16) ^ ((r & 7) << 4))) = wv2[p];
    }
  }
  __syncthreads();
#pragma unroll
  for (int kt = 0; kt < 4; ++kt) {
    const int koff2 = (kt * 32 + lq * 8) * 2;
    short8 a = *(const short8*)((const char*)shA + ((arow * 256 + koff2) ^ axor));
#pragma unroll
    for (int j = 0; j < 7; ++j) {
      int wrow = j * 16 + l16;
      short8 b = *(const short8*)((const char*)shW + ((wrow * 256 + koff2) ^ ((wrow & 7) << 4)));
      acc3[j] = __builtin_amdgcn_mfma_f32_16x16x32_bf16(a, b, acc3[j], 0, 0, 0);
    }
  }
  __syncthreads();                 // done reading shW -> reuse as bounce buffer

  // ---- bias + stats + bounce tile to LDS [64][244] ----
  ushort* shB = shW;
  float s[15], ss[15];
#pragma unroll
  for (int j = 0; j < 15; ++j) { s[j] = 0.f; ss[j] = 0.f; }
  const int rowb = wid * 16 + lq * 4;
#pragma unroll
  for (int j = 0; j < 15; ++j) {
    int col = j * 16 + l16;
    float bias = b2[col];
#pragma unroll
    for (int reg = 0; reg < 4; ++reg) {
      float v = (j < 8 ? acc2[j][reg] : acc3[j - 8][reg]) + bias;
      shB[(rowb + reg) * 244 + col] = f2bf(v);
      if (r0 + rowb + reg < Mpts) { s[j] += v; ss[j] += v * v; }
    }
  }
  __syncthreads();

  // ---- coalesced cw stores: 1920 x 16B chunks ----
  {
    char* cwB = (char*)cw + (size_t)r0 * 480;
#pragma unroll
    for (int i = 0; i < 8; ++i) {
      int gid = i * 256 + t;
      if (gid < 1920) {
        int row = gid / 30;
        int rem = (gid - row * 30) * 16;
        if (r0 + row < Mpts) {
          uint4 v = *(const uint4*)((const char*)shB + row * 488 + rem);
          *(uint4*)(cwB + (size_t)row * 480 + rem) = v;
        }
      }
    }
  }

  // ---- stats reduce + replicated atomics ----
#pragma unroll
  for (int j = 0; j < 15; ++j) {
    for (int off = 32; off > 0; off >>= 1) {
      s[j]  += __shfl_xor(s[j],  off);
      ss[j] += __shfl_xor(ss[j], off);
    }
  }
  if (lane == 0) {
#pragma unroll
    for (int j = 0; j < 15; ++j) { red[0][j][wid] = s[j]; red[1][j][wid] = ss[j]; }
  }
  __syncthreads();
  float* st = stats + (blockIdx.x & 7) * 64;
  if (t < 15) {
    float S = red[0][t][0] + red[0][t][1] + red[0][t][2] + red[0][t][3];
    atomicAdd(&st[t], S);
  } else if (t >= 32 && t < 47) {
    int j = t - 32;
    float SS = red[1][j][0] + red[1][j][1] + red[1][j][2] + red[1][j][3];
    atomicAdd(&st[32 + j], SS);
  }
}

// ====== K3: half-split gather-sum from split arrays (full-line rows) =========
__global__ __launch_bounds__(256) void k3_out(
    const ushort* __restrict__ sfbL, const ushort* __restrict__ sfbH,
    const int* __restrict__ nb, const u32* __restrict__ geomP,
    const float* __restrict__ gn_w, const float* __restrict__ gn_b,
    const float* __restrict__ stats, const ushort* __restrict__ cw,
    float* __restrict__ out)
{
  __shared__ float Atab[255], Btab[255];        // stride 17
  __shared__ float mus[16], rss[16];
  __shared__ float wtab[4][2][8][33];           // [wave][pt][chunk][h+pad]
  const int t = threadIdx.x;

  if (t < 15) {
    float S = 0.f, SS = 0.f;
#pragma unroll
    for (int r = 0; r < 8; ++r) { S += stats[r * 64 + t]; SS += stats[r * 64 + 32 + t]; }
    const float inv = 1.0f / (16.0f * (float)Mpts);
    float mu = S * inv;
    float var = SS * inv - mu * mu;
    mus[t] = mu;
    rss[t] = rsqrtf(var + 1e-5f);
  }
  __syncthreads();
  if (t < 240) {
    int k = t >> 4, c = t & 15;
    float a = rss[k] * gn_w[t];
    Atab[k * 17 + c] = a;
    Btab[k * 17 + c] = gn_b[t] - mus[k] * a;
  }
  __syncthreads();

  const int half = (blockIdx.x >= 6250) ? 1 : 0;
  const int pblk = blockIdx.x - half * 6250;
  const int wid = t >> 6, lane = t & 63;
  const int mbase = pblk * 8 + wid * 2;
  const int gtid = pblk * 256 + t;              // == mbase*32 + lane
  const int ch = lane & 7, hlane = (lane >> 3) & 3, p = lane >> 5;
  const int half8 = half * 8;

  u32 g = geomP[gtid];
  int idxv = nb[gtid]; if (idxv > Npts) idxv = Npts;

  // ---- issue 8 gathers from the half's own 128B-row array ----
  const uint4* fb = (const uint4*)(half ? sfbH : sfbL);
  uint4 fv[8];
#pragma unroll
  for (int j = 0; j < 8; ++j) {
    int ih = __shfl(idxv, (p << 5) | (hlane + 4 * j));
    fv[j] = fb[ih * 8 + ch];                    // row = 8 uint4 = 128 B
  }

  // ---- build wtab for both points while gathers fly (wave-private) ----
  {
    int h = lane >> 1, c0 = (lane & 1) * 4;
#pragma unroll
    for (int q = 0; q < 2; ++q) {
      u32 gp = __shfl((int)g, (q << 5) | h);
      int kh = gp & 15;
      float wI = __uint_as_float(gp & 0xFFFFFFF0u);
      uint2 cwv = *(const uint2*)(cw + (size_t)(mbase + q) * NCW + kh * 16 + half8 + c0);
      const float* Ar = &Atab[kh * 17 + half8 + c0];
      const float* Br = &Btab[kh * 17 + half8 + c0];
      float v0 = __uint_as_float(cwv.x << 16);
      float v1 = __uint_as_float(cwv.x & 0xffff0000u);
      float v2 = __uint_as_float(cwv.y << 16);
      float v3 = __uint_as_float(cwv.y & 0xffff0000u);
      wtab[wid][q][c0 + 0][h] = fmaf(v0, Ar[0], Br[0]) * wI;
      wtab[wid][q][c0 + 1][h] = fmaf(v1, Ar[1], Br[1]) * wI;
      wtab[wid][q][c0 + 2][h] = fmaf(v2, Ar[2], Br[2]) * wI;
      wtab[wid][q][c0 + 3][h] = fmaf(v3, Ar[3], Br[3]) * wI;
    }
  }

  asm volatile("" :: "v"(fv[0].x), "v"(fv[1].x), "v"(fv[2].x), "v"(fv[3].x),
                     "v"(fv[4].x), "v"(fv[5].x), "v"(fv[6].x), "v"(fv[7].x));

  // ---- main: 8 iters, 1 ds_read + masked decode + 4 pk_fma ----
  f32x2 a0 = {0.f, 0.f}, a1 = {0.f, 0.f}, a2 = {0.f, 0.f}, a3 = {0.f, 0.f};
#pragma unroll
  for (int j = 0; j < 8; ++j) {
    float w = wtab[wid][p][ch][hlane + 4 * j];
    f32x2 w2 = {w, w};
    u32 ux = fv[j].x, uy = fv[j].y, uz = fv[j].z, uw = fv[j].w;
    f32x2 q0 = {__uint_as_float(ux << 16), __uint_as_float(ux & 0xffff0000u)};
    f32x2 q1 = {__uint_as_float(uy << 16), __uint_as_float(uy & 0xffff0000u)};
    f32x2 q2 = {__uint_as_float(uz << 16), __uint_as_float(uz & 0xffff0000u)};
    f32x2 q3 = {__uint_as_float(uw << 16), __uint_as_float(uw & 0xffff0000u)};
    a0 = __builtin_elementwise_fma(q0, w2, a0);
    a1 = __builtin_elementwise_fma(q1, w2, a1);
    a2 = __builtin_elementwise_fma(q2, w2, a2);
    a3 = __builtin_elementwise_fma(q3, w2, a3);
  }
#pragma unroll
  for (int off = 8; off <= 16; off <<= 1) {
    a0[0] += __shfl_xor(a0[0], off); a0[1] += __shfl_xor(a0[1], off);
    a1[0] += __shfl_xor(a1[0], off); a1[1] += __shfl_xor(a1[1], off);
    a2[0] += __shfl_xor(a2[0], off); a2[1] += __shfl_xor(a2[1], off);
    a3[0] += __shfl_xor(a3[0], off); a3[1] += __shfl_xor(a3[1], off);
  }
  if ((lane & 24) == 0) {
    float* op = out + (size_t)(mbase + p) * Cc + half * 64 + ch * 8;
    float4 o0; o0.x = a0[0]; o0.y = a0[1]; o0.z = a1[0]; o0.w = a1[1];
    float4 o1; o1.x = a2[0]; o1.y = a2[1]; o1.z = a3[0]; o1.w = a3[1];
    *(float4*)(op)     = o0;
    *(float4*)(op + 4) = o1;
  }
}

// ================= launcher ==================================================
extern "C" void kernel_launch(void* const* d_in, const int* in_sizes, int n_in,
                              void* d_out, int out_size, void* d_ws, size_t ws_size,
                              hipStream_t stream) {
  const float* q_pts  = (const float*)d_in[0];
  const float* s_pts  = (const float*)d_in[1];
  const float* sfeat  = (const float*)d_in[2];
  const int*   nb     = (const int*)d_in[3];
  const float* kp     = (const float*)d_in[4];
  const float* W1     = (const float*)d_in[5];
  const float* b1     = (const float*)d_in[6];
  const float* W2     = (const float*)d_in[7];
  const float* b2     = (const float*)d_in[8];
  const float* gn_w   = (const float*)d_in[9];
  const float* gn_b   = (const float*)d_in[10];
  float* out   = (float*)d_out;

  // ws layout (bytes):
  //   0          stats   (8 replicas x 64 f32, padded to 4096)
  //   4096       sfbL    bf16 (50000+1)x64 = 6,400,128
  //   6404224    sfbH    bf16 (50000+1)x64 = 6,400,128
  //   12804352   W1t     bf16 128x128 = 32768
  //   12837120   W2t     bf16 240x128 = 61440
  //   12898560   cw      bf16 50000x240 = 24,000,000
  //   36898560   geomP   u32 50000x32 = 6,400,000
  char* wsb = (char*)d_ws;
  float*  stats = (float*)wsb;
  ushort* sfbL  = (ushort*)(wsb + 4096);
  ushort* sfbH  = (ushort*)(wsb + 6404224);
  ushort* W1t   = (ushort*)(wsb + 12804352);
  ushort* W2t   = (ushort*)(wsb + 12837120);
  ushort* cwb   = (ushort*)(wsb + 12898560);
  u32*    geomP = (u32*)   (wsb + 36898560);

  k0_pre<<<5, 256, 0, stream>>>(W1, W2, sfbL, sfbH, W1t, W2t, stats);
  k1_mix<<<NBLK1 + 6250, 256, 0, stream>>>(sfeat, W1t, b1, W2t, b2,
                                           sfbL, sfbH, cwb, stats,
                                           q_pts, s_pts, nb, kp, geomP);
  k3_out<<<12500, 256, 0, stream>>>(sfbL, sfbH, nb, geomP, gn_w, gn_b,
                                    stats, cwb, out);
}